// Round 6
// baseline (6481.820 us; speedup 1.0000x reference)
//
#include <hip/hip_runtime.h>
#include <hip/hip_bf16.h>
#include <stdint.h>
#include <stddef.h>

using bf16  = __hip_bfloat16;
using bf162 = __hip_bfloat162;

// ---------- helpers ----------
__device__ __forceinline__ void stOut(float* p, float v) { *p = v; }
__device__ __forceinline__ void stOut(bf16* p, float v)  { *p = __float2bfloat16(v); }

struct __align__(16) bf16x8 { bf162 a, b, c, d; };

__device__ __forceinline__ void bf8_to_f(const bf16* p, float* o) {
    bf16x8 v = *reinterpret_cast<const bf16x8*>(p);
    o[0] = __bfloat162float(v.a.x); o[1] = __bfloat162float(v.a.y);
    o[2] = __bfloat162float(v.b.x); o[3] = __bfloat162float(v.b.y);
    o[4] = __bfloat162float(v.c.x); o[5] = __bfloat162float(v.c.y);
    o[6] = __bfloat162float(v.d.x); o[7] = __bfloat162float(v.d.y);
}

__device__ __forceinline__ float wred_sum(float v) {
    #pragma unroll
    for (int o = 32; o > 0; o >>= 1) v += __shfl_xor(v, o);
    return v;
}

__device__ __forceinline__ unsigned enc_f(float f) {
    unsigned u = __float_as_uint(f);
    return (u & 0x80000000u) ? ~u : (u | 0x80000000u);
}
__device__ __forceinline__ float dec_f(unsigned e) {
    unsigned u = (e & 0x80000000u) ? (e & 0x7fffffffu) : ~e;
    return __uint_as_float(u);
}

__device__ __forceinline__ float lrelu(float x) { return (x > 0.f) ? x : 0.2f * x; }

// ---------- edge dtype detection: count zeros among first 1024 odd int32 words ----------
// int64 data -> odd words are high halves -> ~all zero. int32 -> src values, ~all nonzero.
__global__ void detect_kernel(const int* __restrict__ ei, int E, int* __restrict__ flags) {
    __shared__ int zc;
    if (threadIdx.x == 0) zc = 0;
    __syncthreads();
    int nodd = E / 2; if (nodd > 1024) nodd = 1024;
    for (int i = threadIdx.x; i < nodd; i += blockDim.x)
        if (ei[2 * i + 1] == 0) atomicAdd(&zc, 1);
    __syncthreads();
    if (threadIdx.x == 0) flags[0] = (zc > nodd / 2) ? 1 : 0;
}

// ---------- edge conversion -> clamped int32 src/dst ----------
__global__ void conv_edges_kernel(const int* __restrict__ ei, int* __restrict__ src32,
                                  int* __restrict__ dst32, int E, int N,
                                  const int* __restrict__ flags) {
    const int e = blockIdx.x * blockDim.x + threadIdx.x;
    if (e >= E) return;
    int s, d;
    if (flags[0]) { s = ei[2 * e]; d = ei[2 * (E + e)]; }
    else          { s = ei[e];     d = ei[E + e]; }
    src32[e] = (s < 0) ? 0 : ((s >= N) ? N - 1 : s);
    dst32[e] = (d < 0) ? 0 : ((d >= N) ? N - 1 : d);
}

// ---------- f32 GEMM: C[M,Nn] = A[M,K] @ B[K,Nn] (+bias) ----------
template <typename CT>
__global__ __launch_bounds__(64) void gemm_f32_kernel(
    const float* __restrict__ A, int lda,
    const float* __restrict__ B, int ldb,
    const float* __restrict__ bias,
    CT* __restrict__ C, int ldc,
    int M, int Nn, int K)
{
    const int n2 = (blockIdx.x * 64 + threadIdx.x) * 2;
    if (n2 >= Nn) return;
    const int m0 = blockIdx.y * 4;
    const float* A0 = A + (size_t)m0 * lda;
    const float* A1 = A0 + lda;
    const float* A2 = A1 + lda;
    const float* A3 = A2 + lda;
    const float* Bp = B + n2;
    float a00=0.f,a01=0.f,a10=0.f,a11=0.f,a20=0.f,a21=0.f,a30=0.f,a31=0.f;
    #pragma unroll 4
    for (int k = 0; k < K; ++k) {
        float2 bb = *reinterpret_cast<const float2*>(Bp + (size_t)k * ldb);
        float x0 = A0[k], x1 = A1[k], x2 = A2[k], x3 = A3[k];
        a00 = fmaf(x0, bb.x, a00); a01 = fmaf(x0, bb.y, a01);
        a10 = fmaf(x1, bb.x, a10); a11 = fmaf(x1, bb.y, a11);
        a20 = fmaf(x2, bb.x, a20); a21 = fmaf(x2, bb.y, a21);
        a30 = fmaf(x3, bb.x, a30); a31 = fmaf(x3, bb.y, a31);
    }
    float bz0 = 0.f, bz1 = 0.f;
    if (bias) { bz0 = bias[n2]; bz1 = bias[n2 + 1]; }
    float r[4][2] = {{a00+bz0,a01+bz1},{a10+bz0,a11+bz1},{a20+bz0,a21+bz1},{a30+bz0,a31+bz1}};
    #pragma unroll
    for (int i = 0; i < 4; ++i) {
        int m = m0 + i;
        if (m >= M) break;
        stOut(&C[(size_t)m * ldc + n2],     r[i][0]);
        stOut(&C[(size_t)m * ldc + n2 + 1], r[i][1]);
    }
}

// ---------- V[k,h] = sum_c W[k, h*128+c] * att[h*128+c] ----------
__global__ void make_v_kernel(const float* __restrict__ W, const float* __restrict__ att,
                              float* __restrict__ V, int K)
{
    int t = blockIdx.x * blockDim.x + threadIdx.x;
    if (t >= K * 4) return;
    int k = t >> 2, h = t & 3;
    float s = 0.f;
    const float* wp = W + (size_t)k * 512 + h * 128;
    const float* ap = att + h * 128;
    #pragma unroll 4
    for (int c = 0; c < 128; ++c)
        s = fmaf(wp[c], ap[c], s);
    V[k * 4 + h] = s;
}

// ---------- a_s / a_d logits: one wave per node ----------
__global__ __launch_bounds__(64) void logits_kernel(
    const float* __restrict__ X, int ld,
    const float* __restrict__ Vs, const float* __restrict__ Vd,
    float* __restrict__ a_s, float* __restrict__ a_d, int K)
{
    const int n = blockIdx.x, lane = threadIdx.x;
    float ss0=0,ss1=0,ss2=0,ss3=0,dd0=0,dd1=0,dd2=0,dd3=0;
    const float* xr = X + (size_t)n * ld;
    for (int k = lane; k < K; k += 64) {
        float xv = xr[k];
        const float4 vs = *reinterpret_cast<const float4*>(Vs + (size_t)k * 4);
        const float4 vd = *reinterpret_cast<const float4*>(Vd + (size_t)k * 4);
        ss0 = fmaf(xv, vs.x, ss0); ss1 = fmaf(xv, vs.y, ss1);
        ss2 = fmaf(xv, vs.z, ss2); ss3 = fmaf(xv, vs.w, ss3);
        dd0 = fmaf(xv, vd.x, dd0); dd1 = fmaf(xv, vd.y, dd1);
        dd2 = fmaf(xv, vd.z, dd2); dd3 = fmaf(xv, vd.w, dd3);
    }
    ss0 = wred_sum(ss0); ss1 = wred_sum(ss1); ss2 = wred_sum(ss2); ss3 = wred_sum(ss3);
    dd0 = wred_sum(dd0); dd1 = wred_sum(dd1); dd2 = wred_sum(dd2); dd3 = wred_sum(dd3);
    if (lane == 0) {
        a_s[n*4+0]=ss0; a_s[n*4+1]=ss1; a_s[n*4+2]=ss2; a_s[n*4+3]=ss3;
        a_d[n*4+0]=dd0; a_d[n*4+1]=dd1; a_d[n*4+2]=dd2; a_d[n*4+3]=dd3;
    }
}

__global__ void bias_sum_kernel(const float* __restrict__ a, const float* __restrict__ b,
                                float* __restrict__ o) {
    int i = blockIdx.x * blockDim.x + threadIdx.x;
    if (i < 512) o[i] = a[i] + b[i];
}

__global__ void init_md_kernel(unsigned* __restrict__ menc, float* __restrict__ denom, int n4) {
    int i = blockIdx.x * blockDim.x + threadIdx.x;
    if (i < n4) { menc[i] = enc_f(-1e30f); denom[i] = 0.f; }
}

__global__ void edge_max_kernel(const int* __restrict__ src, const int* __restrict__ dst,
                                const float* __restrict__ a_s, const float* __restrict__ a_d,
                                float* __restrict__ lbuf, unsigned* __restrict__ menc, int E)
{
    int e = blockIdx.x * blockDim.x + threadIdx.x;
    if (e >= E) return;
    int s = src[e], d = dst[e];
    float4 as = *reinterpret_cast<const float4*>(a_s + (size_t)s * 4);
    float4 ad = *reinterpret_cast<const float4*>(a_d + (size_t)d * 4);
    float4 l;
    l.x = lrelu(as.x + ad.x);
    l.y = lrelu(as.y + ad.y);
    l.z = lrelu(as.z + ad.z);
    l.w = lrelu(as.w + ad.w);
    *reinterpret_cast<float4*>(lbuf + (size_t)e * 4) = l;
    atomicMax(&menc[d * 4 + 0], enc_f(l.x));
    atomicMax(&menc[d * 4 + 1], enc_f(l.y));
    atomicMax(&menc[d * 4 + 2], enc_f(l.z));
    atomicMax(&menc[d * 4 + 3], enc_f(l.w));
}

__global__ void edge_expsum_kernel(const int* __restrict__ dst,
                                   const unsigned* __restrict__ menc,
                                   float* __restrict__ lbuf, float* __restrict__ denom, int E)
{
    int e = blockIdx.x * blockDim.x + threadIdx.x;
    if (e >= E) return;
    int d = dst[e];
    float4 l = *reinterpret_cast<const float4*>(lbuf + (size_t)e * 4);
    float4 w;
    w.x = expf(l.x - dec_f(menc[d * 4 + 0]));
    w.y = expf(l.y - dec_f(menc[d * 4 + 1]));
    w.z = expf(l.z - dec_f(menc[d * 4 + 2]));
    w.w = expf(l.w - dec_f(menc[d * 4 + 3]));
    *reinterpret_cast<float4*>(lbuf + (size_t)e * 4) = w;
    atomicAdd(&denom[d * 4 + 0], w.x);
    atomicAdd(&denom[d * 4 + 1], w.y);
    atomicAdd(&denom[d * 4 + 2], w.z);
    atomicAdd(&denom[d * 4 + 3], w.w);
}

__global__ __launch_bounds__(64) void edge_scatter_kernel(
    const int* __restrict__ src, const int* __restrict__ dst,
    const float* __restrict__ lbuf, const float* __restrict__ denom,
    const bf16* __restrict__ xs, float* __restrict__ hout, int E)
{
    const int e = blockIdx.x;
    if (e >= E) return;
    const int lane = threadIdx.x;
    const int s = src[e], d = dst[e];
    const int c0 = lane * 8;
    const int h  = lane >> 4;
    const float w   = lbuf[(size_t)e * 4 + h];
    const float den = denom[(size_t)d * 4 + h];
    const float coef = w / (den + 1e-16f);
    float xv[8];
    bf8_to_f(xs + (size_t)s * 512 + c0, xv);
    float* hp = hout + (size_t)d * 512 + c0;
    #pragma unroll
    for (int t = 0; t < 8; ++t) atomicAdd(&hp[t], coef * xv[t]);
}

__global__ __launch_bounds__(64) void ln_relu_kernel(
    const float* __restrict__ in, const float* __restrict__ g,
    const float* __restrict__ b, float* __restrict__ outp)
{
    const int n = blockIdx.x, lane = threadIdx.x;
    const int c0 = lane * 8;
    const float* ip = in + (size_t)n * 512 + c0;
    float v[8];
    float4 p0 = *reinterpret_cast<const float4*>(ip);
    float4 p1 = *reinterpret_cast<const float4*>(ip + 4);
    v[0]=p0.x; v[1]=p0.y; v[2]=p0.z; v[3]=p0.w; v[4]=p1.x; v[5]=p1.y; v[6]=p1.z; v[7]=p1.w;
    float s = 0.f;
    #pragma unroll
    for (int t = 0; t < 8; ++t) s += v[t];
    s = wred_sum(s);
    const float mu = s * (1.0f / 512.0f);
    float q = 0.f;
    #pragma unroll
    for (int t = 0; t < 8; ++t) { float dlt = v[t] - mu; q = fmaf(dlt, dlt, q); }
    q = wred_sum(q);
    const float sc = rsqrtf(q * (1.0f / 512.0f) + 1e-5f);
    float4 g0 = *reinterpret_cast<const float4*>(g + c0);
    float4 g1 = *reinterpret_cast<const float4*>(g + c0 + 4);
    float4 b0 = *reinterpret_cast<const float4*>(b + c0);
    float4 b1 = *reinterpret_cast<const float4*>(b + c0 + 4);
    const float gv[8] = {g0.x,g0.y,g0.z,g0.w,g1.x,g1.y,g1.z,g1.w};
    const float bv[8] = {b0.x,b0.y,b0.z,b0.w,b1.x,b1.y,b1.z,b1.w};
    float* op = outp + (size_t)n * 512 + c0;
    #pragma unroll
    for (int t = 0; t < 8; ++t)
        op[t] = fmaxf(0.f, fmaf((v[t] - mu) * sc, gv[t], bv[t]));
}

// ---------- fused head; OUTPUTS ARE FLOAT32 ----------
__global__ __launch_bounds__(256) void head_kernel(
    const float* __restrict__ hB,
    const float* __restrict__ agg_W, const float* __restrict__ agg_b,
    const float* __restrict__ dr_W,  const float* __restrict__ dr_b,
    const float* __restrict__ dp_W,  const float* __restrict__ dp_b,
    const float* __restrict__ rr_W,  const float* __restrict__ rr_b,
    const float* __restrict__ rp_W,  const float* __restrict__ rp_b,
    float* __restrict__ out_rna, float* __restrict__ out_prot, float* __restrict__ out_emb)
{
    __shared__ float h[512];
    __shared__ float part[256];
    __shared__ float emb[128];
    __shared__ float tr[128];
    __shared__ float tp[128];
    const int n = blockIdx.x;
    const int t = threadIdx.x;

    {
        const float* hp = hB + (size_t)n * 512;
        h[t]       = hp[t];
        h[t + 256] = hp[t + 256];
    }
    __syncthreads();

    {
        const int c = t & 127, half = t >> 7;
        float s = 0.f;
        const float* w  = agg_W + (size_t)(half * 256) * 128 + c;
        const float* hh = h + half * 256;
        #pragma unroll 4
        for (int k = 0; k < 256; ++k) s = fmaf(hh[k], w[(size_t)k * 128], s);
        part[t] = s;
    }
    __syncthreads();
    if (t < 128) {
        float e = fmaxf(0.f, part[t] + part[t + 128] + agg_b[t]);
        emb[t] = e;
        out_emb[(size_t)n * 128 + t] = e;
    }
    __syncthreads();

    {
        if (t < 128) {
            float s = dr_b[t];
            const float* w = dr_W + t;
            #pragma unroll 4
            for (int k = 0; k < 128; ++k) s = fmaf(emb[k], w[(size_t)k * 128], s);
            tr[t] = s;
        } else {
            const int c = t - 128;
            float s = dp_b[c];
            const float* w = dp_W + c;
            #pragma unroll 4
            for (int k = 0; k < 128; ++k) s = fmaf(emb[k], w[(size_t)k * 128], s);
            tp[c] = s;
        }
    }
    __syncthreads();

    {
        float* orow = out_rna + (size_t)n * 2000;
        for (int c = t; c < 2000; c += 256) {
            float s = rr_b[c];
            const float* w = rr_W + c;
            #pragma unroll 4
            for (int k = 0; k < 128; ++k) s = fmaf(tr[k], w[(size_t)k * 2000], s);
            orow[c] = s;
        }
    }
    {
        if (t < 100) {
            float s = rp_b[t];
            const float* w = rp_W + t;
            #pragma unroll 4
            for (int k = 0; k < 128; ++k) s = fmaf(tp[k], w[(size_t)k * 100], s);
            out_prot[(size_t)n * 100 + t] = s;
        }
    }
}

// ---------- launcher ----------
extern "C" void kernel_launch(void* const* d_in, const int* in_sizes, int n_in,
                              void* d_out, int out_size, void* d_ws, size_t ws_size,
                              hipStream_t stream)
{
    (void)n_in; (void)out_size; (void)ws_size;
    const float* x   = (const float*)d_in[0];
    const int*   ei  = (const int*)d_in[1];

    const float* W_rna  = (const float*)d_in[2];
    const float* b_rna  = (const float*)d_in[3];
    const float* W_prot = (const float*)d_in[4];
    const float* b_prot = (const float*)d_in[5];
    const float* c1_Ws  = (const float*)d_in[6];
    const float* c1_Wd  = (const float*)d_in[7];
    const float* c1_as  = (const float*)d_in[8];
    const float* c1_ad  = (const float*)d_in[9];
    const float* c1_b   = (const float*)d_in[10];
    const float* l1_W   = (const float*)d_in[11];
    const float* l1_b   = (const float*)d_in[12];
    const float* ln_g   = (const float*)d_in[13];
    const float* ln_b   = (const float*)d_in[14];
    const float* c2_Ws  = (const float*)d_in[15];
    const float* c2_Wd  = (const float*)d_in[16];
    const float* c2_as  = (const float*)d_in[17];
    const float* c2_ad  = (const float*)d_in[18];
    const float* c2_b   = (const float*)d_in[19];
    const float* l2_W   = (const float*)d_in[20];
    const float* l2_b   = (const float*)d_in[21];
    const float* agg_W  = (const float*)d_in[22];
    const float* agg_b  = (const float*)d_in[23];
    const float* dr_W   = (const float*)d_in[24];
    const float* dr_b   = (const float*)d_in[25];
    const float* dp_W   = (const float*)d_in[26];
    const float* dp_b   = (const float*)d_in[27];
    const float* rr_W   = (const float*)d_in[28];
    const float* rr_b   = (const float*)d_in[29];
    const float* rp_W   = (const float*)d_in[30];
    const float* rp_b   = (const float*)d_in[31];

    const int N = in_sizes[0] / 2100;   // 10000
    const int E = in_sizes[1] / 2;      // 160000

    char* wsp = (char*)d_ws;
    size_t off = 0;
    auto alloc = [&](size_t bytes) -> void* {
        void* p = wsp + off;
        off += (bytes + 255) & ~(size_t)255;
        return p;
    };
    int*      flags = (int*)     alloc(16);
    int*      src32 = (int*)     alloc((size_t)E * 4);
    int*      dst32 = (int*)     alloc((size_t)E * 4);
    float*    xin   = (float*)   alloc((size_t)N * 256 * 4);
    float*    hA    = (float*)   alloc((size_t)N * 512 * 4);
    float*    hB    = (float*)   alloc((size_t)N * 512 * 4);
    bf16*     xs    = (bf16*)    alloc((size_t)N * 512 * 2);
    float*    a_s   = (float*)   alloc((size_t)N * 4 * 4);
    float*    a_d   = (float*)   alloc((size_t)N * 4 * 4);
    float*    Vs    = (float*)   alloc(512 * 4 * 4);
    float*    Vd    = (float*)   alloc(512 * 4 * 4);
    unsigned* menc  = (unsigned*)alloc((size_t)N * 4 * 4);
    float*    denom = (float*)   alloc((size_t)N * 4 * 4);
    float*    lbuf  = (float*)   alloc((size_t)E * 4 * 4);
    float*    bsum1 = (float*)   alloc(512 * 4);
    float*    bsum2 = (float*)   alloc(512 * 4);

    const dim3 blk64(64, 1, 1);
    const dim3 blk256(256, 1, 1);
    const int MY = (N + 3) / 4;
    const dim3 gE((E + 255) / 256);
    const dim3 gN4((N * 4 + 255) / 256);

    // f32 output layout: rna [N,2000] | prot [N,100] | emb [N,128]
    float* out0 = (float*)d_out;
    float* out1 = out0 + (size_t)N * 2000;
    float* out2 = out1 + (size_t)N * 100;

    // ---- edges ----
    detect_kernel<<<dim3(1), blk256, 0, stream>>>(ei, E, flags);
    conv_edges_kernel<<<gE, blk256, 0, stream>>>(ei, src32, dst32, E, N, flags);

    // ---- embed ----
    gemm_f32_kernel<float><<<dim3(1, MY), blk64, 0, stream>>>(
        x, 2100, W_rna, 128, b_rna, xin, 256, N, 128, 2000);
    gemm_f32_kernel<float><<<dim3(1, MY), blk64, 0, stream>>>(
        x + 2000, 2100, W_prot, 128, b_prot, xin + 128, 256, N, 128, 100);

    // ---- block 1 ----
    make_v_kernel<<<dim3(4), blk256, 0, stream>>>(c1_Ws, c1_as, Vs, 256);
    make_v_kernel<<<dim3(4), blk256, 0, stream>>>(c1_Wd, c1_ad, Vd, 256);
    logits_kernel<<<dim3(N), blk64, 0, stream>>>(xin, 256, Vs, Vd, a_s, a_d, 256);
    bias_sum_kernel<<<dim3(2), blk256, 0, stream>>>(l1_b, c1_b, bsum1);
    gemm_f32_kernel<bf16><<<dim3(4, MY), blk64, 0, stream>>>(
        xin, 256, c1_Ws, 512, nullptr, xs, 512, N, 512, 256);
    gemm_f32_kernel<float><<<dim3(4, MY), blk64, 0, stream>>>(
        xin, 256, l1_W, 512, bsum1, hB, 512, N, 512, 256);
    init_md_kernel<<<gN4, blk256, 0, stream>>>(menc, denom, N * 4);
    edge_max_kernel<<<gE, blk256, 0, stream>>>(src32, dst32, a_s, a_d, lbuf, menc, E);
    edge_expsum_kernel<<<gE, blk256, 0, stream>>>(dst32, menc, lbuf, denom, E);
    edge_scatter_kernel<<<dim3(E), blk64, 0, stream>>>(src32, dst32, lbuf, denom, xs, hB, E);
    ln_relu_kernel<<<dim3(N), blk64, 0, stream>>>(hB, ln_g, ln_b, hA);

    // ---- block 2 ----
    make_v_kernel<<<dim3(8), blk256, 0, stream>>>(c2_Ws, c2_as, Vs, 512);
    make_v_kernel<<<dim3(8), blk256, 0, stream>>>(c2_Wd, c2_ad, Vd, 512);
    logits_kernel<<<dim3(N), blk64, 0, stream>>>(hA, 512, Vs, Vd, a_s, a_d, 512);
    bias_sum_kernel<<<dim3(2), blk256, 0, stream>>>(l2_b, c2_b, bsum2);
    gemm_f32_kernel<bf16><<<dim3(4, MY), blk64, 0, stream>>>(
        hA, 512, c2_Ws, 512, nullptr, xs, 512, N, 512, 512);
    gemm_f32_kernel<float><<<dim3(4, MY), blk64, 0, stream>>>(
        hA, 512, l2_W, 512, bsum2, hB, 512, N, 512, 512);
    init_md_kernel<<<gN4, blk256, 0, stream>>>(menc, denom, N * 4);
    edge_max_kernel<<<gE, blk256, 0, stream>>>(src32, dst32, a_s, a_d, lbuf, menc, E);
    edge_expsum_kernel<<<gE, blk256, 0, stream>>>(dst32, menc, lbuf, denom, E);
    edge_scatter_kernel<<<dim3(E), blk64, 0, stream>>>(src32, dst32, lbuf, denom, xs, hB, E);

    // ---- head (f32 outputs) ----
    head_kernel<<<dim3(N), blk256, 0, stream>>>(
        hB, agg_W, agg_b, dr_W, dr_b, dp_W, dp_b, rr_W, rr_b, rp_W, rp_b,
        out0, out1, out2);
}